// Round 10
// baseline (29.835 us; speedup 1.0000x reference)
//
#include <hip/hip_runtime.h>

// Problem constants (HierarchicalIntentClassifier: B=8192, D=768, E=8, K=32)
#define BB 8192
#define DD 768
#define EE 8
#define KK 32
#define BM 32              // rows per block
#define NBLK (BB / BM)     // 256 blocks = 1 per CU
#define NSTEP (DD / 32)    // 24 K-steps
#define PF 8               // B-prefetch depth (K-steps held in VGPRs)

typedef short    short4s __attribute__((ext_vector_type(4)));
typedef short    short8 __attribute__((ext_vector_type(8)));
typedef float    f32x4  __attribute__((ext_vector_type(4)));
typedef float    f32x8  __attribute__((ext_vector_type(8)));
typedef unsigned short us4 __attribute__((ext_vector_type(4)));

// RNE float -> bf16 bits (finite inputs; no NaN path needed)
__device__ __forceinline__ unsigned short f2bf(float f) {
  unsigned int u = __float_as_uint(f);
  u = (u + 0x7fffu + ((u >> 16) & 1u)) >> 16;
  return (unsigned short)u;
}

// ---------------------------------------------------------------------------
// Pack kernel: sub_W [E][D][K] fp32 -> Bp fragment-linear bf16 (same layout as
// R7/R9, which passed 3x). R10: split 2x finer — each thread produces HALF a
// fragment (4 shorts): t = frag*2 + h; frag = e*3072 + s*128 + half*64 + lane.
// 49152 threads over 192 blocks: shorter per-thread chains, 75% CU coverage.
// Write is short4 at bp + 4*t (linear, coalesced).
// ---------------------------------------------------------------------------
__global__ __launch_bounds__(256) void pack_w(const float* __restrict__ sw,
                                              short* __restrict__ bp) {
  const int t    = blockIdx.x * 256 + threadIdx.x;   // 0 .. 49151
  const int h    = t & 1;                            // which half of fragment
  const int f    = t >> 1;                           // fragment id 0..24575
  const int lane = f & 63;
  const int half = (f >> 6) & 1;
  const int s    = (f >> 7) % NSTEP;
  const int e    = (f >> 7) / NSTEP;
  const int lc   = lane & 15, hi = lane >> 4;
  const int k    = half * 16 + lc;
  const int d0   = s * 32 + hi * 8 + h * 4;
  const float* src = sw + ((size_t)(e * DD + d0)) * KK + k;
  short4s v;
#pragma unroll
  for (int j = 0; j < 4; ++j) v[j] = (short)f2bf(src[(size_t)j * KK]);
  *(short4s*)(bp + (size_t)t * 4) = v;
}

// ---------------------------------------------------------------------------
// Fused kernel: 512 threads (8 waves), BM=32 rows/block, 256 blocks (1/CU).
// R10 change: the B-stream is INDEPENDENT of phase 1 — prefetch the first PF
// K-steps' B-fragments into registers at kernel entry (before the pooled
// loads), so the L2 B-stream overlaps phase 1's L3/HBM loads + VALU work and
// phase 2 starts with zero B cold-start. At 1 block/CU (2 waves/SIMD) the
// VGPR budget is 256/wave — launch_bounds(512,2) tells the allocator so.
// Phase 1: R9's exact passing form (wave w: rows 4w..4w+3, fp32 GEMV +
//          bf16 LDS stash, unroll 1, butterfly reduce — argmax order
//          unchanged to avoid re-rolling tie-rounding dice).
// Phase 2: steps 0..PF-1 MFMA from prefetched regs; steps PF..23 stream
//          inline (unroll 4). Epilogue identical to R9.
// ---------------------------------------------------------------------------
__global__ __launch_bounds__(512, 2) void fused(
    const float* __restrict__ pooled, const float* __restrict__ mW,
    const float* __restrict__ mb, const short* __restrict__ Bp,
    const float* __restrict__ sub_b, const int* __restrict__ sub_sizes,
    float* __restrict__ main_out, float* __restrict__ sub_out) {
  // 776 = 768 + 8 shorts pad (row stride 1552 B): phase-2 ds_read_b128s land
  // uniformly 8 accesses/bank (the structural minimum for b128).
  __shared__ short aS[BM][776];
  __shared__ int   idxS[BM];
  __shared__ int   szS[BM];

  const int t    = threadIdx.x;
  const int w    = t >> 6;
  const int lane = t & 63;
  const int row0 = blockIdx.x * BM;
  const int lc   = lane & 15, hi = lane >> 4;

  // ---- B prefetch: first PF K-steps, issued before anything else ----
  const short* bpw = Bp + (size_t)w * (NSTEP * 1024) + (size_t)lane * 8;
  short8 bpre0[PF], bpre1[PF];
#pragma unroll
  for (int s = 0; s < PF; ++s) {
    bpre0[s] = *(const short8*)(bpw + s * 1024);        // half 0: k = lc
    bpre1[s] = *(const short8*)(bpw + s * 1024 + 512);  // half 1: k = 16+lc
  }

  // ---- Phase 1: main GEMV (fp32) + bf16 stash, 4 rows per wave ----
  f32x8 acc[4] = {};
#pragma unroll 1
  for (int i = 0; i < 3; ++i) {
    const int d = (i * 64 + lane) * 4;
    f32x8 W0 = *(const f32x8*)(mW + (size_t)(d + 0) * EE);
    f32x8 W1 = *(const f32x8*)(mW + (size_t)(d + 1) * EE);
    f32x8 W2 = *(const f32x8*)(mW + (size_t)(d + 2) * EE);
    f32x8 W3 = *(const f32x8*)(mW + (size_t)(d + 3) * EE);
#pragma unroll
    for (int rr = 0; rr < 4; ++rr) {
      const int r = w * 4 + rr;
      f32x4 v = *(const f32x4*)(pooled + (size_t)(row0 + r) * DD + d);
      us4 u;
      u[0] = f2bf(v[0]); u[1] = f2bf(v[1]); u[2] = f2bf(v[2]); u[3] = f2bf(v[3]);
      *(us4*)&aS[r][d] = u;
      acc[rr] += v[0] * W0;
      acc[rr] += v[1] * W1;
      acc[rr] += v[2] * W2;
      acc[rr] += v[3] * W3;
    }
  }
#pragma unroll
  for (int rr = 0; rr < 4; ++rr) {
#pragma unroll
    for (int off = 32; off >= 1; off >>= 1) {
#pragma unroll
      for (int j = 0; j < 8; ++j) acc[rr][j] += __shfl_xor(acc[rr][j], off);
    }
    if (lane == 0) {
      const int r = w * 4 + rr;
      f32x8 res = acc[rr] + *(const f32x8*)mb;
      *(f32x8*)(main_out + (size_t)(row0 + r) * EE) = res;
      float best = res[0];
      int   bi   = 0;
#pragma unroll
      for (int e = 1; e < EE; ++e) {
        if (res[e] > best) { best = res[e]; bi = e; }
      }
      idxS[r] = bi;
      szS[r]  = sub_sizes[bi];
    }
  }
  __syncthreads();

  // ---- Phase 2: MFMA. Wave w = expert w; two M-tiles. ----
  f32x4 c[2][2] = {};   // [mtile][khalf]

  // steps 0..PF-1 from prefetched registers (only A ds_reads on the path)
#pragma unroll
  for (int s = 0; s < PF; ++s) {
    const int dd = s * 32 + hi * 8;
    short8 a0 = *(const short8*)&aS[lc][dd];             // rows 0-15
    short8 a1 = *(const short8*)&aS[16 + lc][dd];        // rows 16-31
    c[0][0] = __builtin_amdgcn_mfma_f32_16x16x32_bf16(a0, bpre0[s], c[0][0], 0, 0, 0);
    c[0][1] = __builtin_amdgcn_mfma_f32_16x16x32_bf16(a0, bpre1[s], c[0][1], 0, 0, 0);
    c[1][0] = __builtin_amdgcn_mfma_f32_16x16x32_bf16(a1, bpre0[s], c[1][0], 0, 0, 0);
    c[1][1] = __builtin_amdgcn_mfma_f32_16x16x32_bf16(a1, bpre1[s], c[1][1], 0, 0, 0);
  }

  // steps PF..NSTEP-1 streamed inline
#pragma unroll 4
  for (int s = PF; s < NSTEP; ++s) {
    short8 b0 = *(const short8*)(bpw + s * 1024);
    short8 b1 = *(const short8*)(bpw + s * 1024 + 512);
    const int dd = s * 32 + hi * 8;
    short8 a0 = *(const short8*)&aS[lc][dd];
    short8 a1 = *(const short8*)&aS[16 + lc][dd];
    c[0][0] = __builtin_amdgcn_mfma_f32_16x16x32_bf16(a0, b0, c[0][0], 0, 0, 0);
    c[0][1] = __builtin_amdgcn_mfma_f32_16x16x32_bf16(a0, b1, c[0][1], 0, 0, 0);
    c[1][0] = __builtin_amdgcn_mfma_f32_16x16x32_bf16(a1, b0, c[1][0], 0, 0, 0);
    c[1][1] = __builtin_amdgcn_mfma_f32_16x16x32_bf16(a1, b1, c[1][1], 0, 0, 0);
  }

  // ---- Epilogue: routed select + bias + size mask; each (row,k) once ----
#pragma unroll
  for (int n = 0; n < 2; ++n) {
    const int k = n * 16 + lc;
    const float bias = sub_b[w * KK + k];
#pragma unroll
    for (int mt = 0; mt < 2; ++mt) {
#pragma unroll
      for (int q = 0; q < 4; ++q) {
        const int rl = mt * 16 + hi * 4 + q;  // C/D: col=lane&15, row=(l>>4)*4+q
        if (idxS[rl] == w) {
          float v = c[mt][n][q] + bias;
          if (k >= szS[rl]) v = 0.f;
          sub_out[(size_t)(row0 + rl) * KK + k] = v;
        }
      }
    }
  }
}

// ---------------------------------------------------------------------------
extern "C" void kernel_launch(void* const* d_in, const int* in_sizes, int n_in,
                              void* d_out, int out_size, void* d_ws, size_t ws_size,
                              hipStream_t stream) {
  const float* pooled   = (const float*)d_in[0];
  const float* main_W   = (const float*)d_in[1];
  const float* main_b   = (const float*)d_in[2];
  const float* sub_W    = (const float*)d_in[3];
  const float* sub_b    = (const float*)d_in[4];
  const int*   sub_size = (const int*)d_in[5];

  float* main_out = (float*)d_out;                    // [B, E]
  float* sub_out  = (float*)d_out + (size_t)BB * EE;  // [B, K]
  short* Bp       = (short*)d_ws;                     // fragment-linear, 384 KB

  pack_w<<<192, 256, 0, stream>>>(sub_W, Bp);
  fused<<<NBLK, 512, 0, stream>>>(pooled, main_W, main_b, Bp, sub_b,
                                  sub_size, main_out, sub_out);
}